// Round 1
// baseline (510.695 us; speedup 1.0000x reference)
//
#include <hip/hip_runtime.h>
#include <math.h>

typedef __attribute__((ext_vector_type(4))) float floatx4;
typedef __attribute__((ext_vector_type(8))) short shortx8;

#define M_TILE 128
#define N_TILE 64
#define BK 32
#define KP 40   // padded k-pitch (elements): 80 B/row -> 16B-aligned frags, ~2-way write conflicts

__device__ __forceinline__ unsigned short f2bf(float f) {
    union { float f; unsigned int u; } v; v.f = f;
    unsigned int r = v.u + 0x7fffu + ((v.u >> 16) & 1u);   // round-to-nearest-even
    return (unsigned short)(r >> 16);
}

__global__ __launch_bounds__(256, 2)
void gru_fused_kernel(const float* __restrict__ X,      // inputs   [8192][1024]
                      const float* __restrict__ H,      // h_tm1    [8192][1024]
                      const float* __restrict__ W,      // kernel   [1024][3072]
                      const float* __restrict__ R,      // rec_kern [1024][3072]
                      const float* __restrict__ bias,   // [2][3072]
                      float* __restrict__ out)          // h        [8192][1024]
{
    __shared__ __attribute__((aligned(16))) unsigned short ldsA[2][M_TILE * KP]; // [x|h][m][k]
    __shared__ __attribute__((aligned(16))) unsigned short ldsW[6][N_TILE * KP]; // [Wz,Wr,Wh,Rz,Rr,Rh][n][k]

    const int tid  = threadIdx.x;
    const int bid  = blockIdx.x;
    const int bn   = bid & 15;        // XCD swizzle: same weight slice -> same XCD
    const int bm   = bid >> 4;
    const int m0   = bm * M_TILE;
    const int n0   = bn * N_TILE;

    const int wid  = tid >> 6;
    const int lane = tid & 63;
    const int wr   = wid >> 1;        // wave row (0..1): 64 rows each
    const int wc   = wid & 1;         // wave col (0..1): 32 cols each
    const int lo   = lane & 15;
    const int quad = lane >> 4;

    floatx4 acc_z[4][2]  = {};   // x_z + rec_z (combined K=2048)
    floatx4 acc_r[4][2]  = {};   // x_r + rec_r
    floatx4 acc_xh[4][2] = {};   // x_h
    floatx4 acc_rh[4][2] = {};   // rec_h

    for (int k0 = 0; k0 < 1024; k0 += BK) {
        // ---- stage A tiles (inputs, h_tm1): 2 x 128x32 fp32 -> bf16, [m][k]
        #pragma unroll
        for (int i = 0; i < 8; ++i) {
            int idx = tid + i * 256;                 // 0..2047
            const float* base = (idx < 1024) ? X : H;
            int rem = idx & 1023;
            int row = rem >> 3;                      // 0..127
            int kq  = rem & 7;                       // float4 index along k
            const float4 v = *(const float4*)(base + (size_t)(m0 + row) * 1024 + k0 + kq * 4);
            ushort4 s;
            s.x = f2bf(v.x); s.y = f2bf(v.y); s.z = f2bf(v.z); s.w = f2bf(v.w);
            *(ushort4*)&ldsA[idx >> 10][row * KP + kq * 4] = s;
        }
        // ---- stage weights: 6 groups of 32(k)x64(n) fp32 -> bf16, transposed to [n][k]
        #pragma unroll
        for (int i = 0; i < 3; ++i) {
            int b   = tid + i * 256;                 // 0..767
            int g   = b >> 7;                        // 0..5
            int rem = b & 127;
            int kb  = rem >> 4;                      // k block of 4 (0..7)
            int c4  = rem & 15;                      // col group of 4
            const float* wb = (g < 3) ? W : R;
            int gm = (g < 3) ? g : g - 3;
            const float* src = wb + (size_t)(k0 + kb * 4) * 3072 + gm * 1024 + n0 + c4 * 4;
            float4 r0 = *(const float4*)(src);
            float4 r1 = *(const float4*)(src + 3072);
            float4 r2 = *(const float4*)(src + 2 * 3072);
            float4 r3 = *(const float4*)(src + 3 * 3072);
            ushort4 s0, s1, s2, s3;                  // 4x4 register transpose
            s0.x=f2bf(r0.x); s0.y=f2bf(r1.x); s0.z=f2bf(r2.x); s0.w=f2bf(r3.x);
            s1.x=f2bf(r0.y); s1.y=f2bf(r1.y); s1.z=f2bf(r2.y); s1.w=f2bf(r3.y);
            s2.x=f2bf(r0.z); s2.y=f2bf(r1.z); s2.z=f2bf(r2.z); s2.w=f2bf(r3.z);
            s3.x=f2bf(r0.w); s3.y=f2bf(r1.w); s3.z=f2bf(r2.w); s3.w=f2bf(r3.w);
            unsigned short* dst = &ldsW[g][0];
            *(ushort4*)&dst[(c4*4+0) * KP + kb*4] = s0;
            *(ushort4*)&dst[(c4*4+1) * KP + kb*4] = s1;
            *(ushort4*)&dst[(c4*4+2) * KP + kb*4] = s2;
            *(ushort4*)&dst[(c4*4+3) * KP + kb*4] = s3;
        }
        __syncthreads();

        shortx8 a_in[4], a_h[4];
        #pragma unroll
        for (int i = 0; i < 4; ++i) {
            a_in[i] = *(const shortx8*)&ldsA[0][(wr*64 + i*16 + lo) * KP + quad*8];
            a_h[i]  = *(const shortx8*)&ldsA[1][(wr*64 + i*16 + lo) * KP + quad*8];
        }
        #pragma unroll
        for (int j = 0; j < 2; ++j) {
            const int nc = (wc*32 + j*16 + lo) * KP + quad*8;
            shortx8 bz  = *(const shortx8*)&ldsW[0][nc];
            shortx8 bre = *(const shortx8*)&ldsW[1][nc];
            shortx8 bh  = *(const shortx8*)&ldsW[2][nc];
            shortx8 rz  = *(const shortx8*)&ldsW[3][nc];
            shortx8 rre = *(const shortx8*)&ldsW[4][nc];
            shortx8 rh  = *(const shortx8*)&ldsW[5][nc];
            #pragma unroll
            for (int i = 0; i < 4; ++i) {
                acc_z[i][j]  = __builtin_amdgcn_mfma_f32_16x16x32_bf16(a_in[i], bz,  acc_z[i][j],  0, 0, 0);
                acc_z[i][j]  = __builtin_amdgcn_mfma_f32_16x16x32_bf16(a_h[i],  rz,  acc_z[i][j],  0, 0, 0);
                acc_r[i][j]  = __builtin_amdgcn_mfma_f32_16x16x32_bf16(a_in[i], bre, acc_r[i][j],  0, 0, 0);
                acc_r[i][j]  = __builtin_amdgcn_mfma_f32_16x16x32_bf16(a_h[i],  rre, acc_r[i][j],  0, 0, 0);
                acc_xh[i][j] = __builtin_amdgcn_mfma_f32_16x16x32_bf16(a_in[i], bh,  acc_xh[i][j], 0, 0, 0);
                acc_rh[i][j] = __builtin_amdgcn_mfma_f32_16x16x32_bf16(a_h[i],  rh,  acc_rh[i][j], 0, 0, 0);
            }
        }
        __syncthreads();
    }

    // ---- epilogue: bias + gates + blend, write h
    #pragma unroll
    for (int j = 0; j < 2; ++j) {
        const int col = n0 + wc*32 + j*16 + lo;
        const float bz  = bias[col]        + bias[3072 + col];   // input_z + rec_z bias
        const float brr = bias[1024 + col] + bias[4096 + col];   // input_r + rec_r bias
        const float b0h = bias[2048 + col];                      // input_h bias
        const float b1h = bias[5120 + col];                      // rec_h bias
        #pragma unroll
        for (int i = 0; i < 4; ++i) {
            const int rowb = m0 + wr*64 + i*16 + quad*4;
            #pragma unroll
            for (int r = 0; r < 4; ++r) {
                const int row = rowb + r;
                float sz = acc_z[i][j][r]  + bz;
                float sr = acc_r[i][j][r]  + brr;
                float xh = acc_xh[i][j][r] + b0h;
                float rh = acc_rh[i][j][r] + b1h;
                float z   = fminf(fmaxf(0.2f * sz + 0.5f, 0.0f), 1.0f);
                float rr2 = fminf(fmaxf(0.2f * sr + 0.5f, 0.0f), 1.0f);
                float pre = xh + rr2 * rh;
                float e   = __expf(2.0f * pre);
                float th  = 1.0f - 2.0f / (e + 1.0f);             // tanh(pre), stable at +/-inf
                float hp  = H[(size_t)row * 1024 + col];
                out[(size_t)row * 1024 + col] = z * hp + (1.0f - z) * th;
            }
        }
    }
}

extern "C" void kernel_launch(void* const* d_in, const int* in_sizes, int n_in,
                              void* d_out, int out_size, void* d_ws, size_t ws_size,
                              hipStream_t stream)
{
    const float* X    = (const float*)d_in[0];
    const float* H    = (const float*)d_in[1];
    const float* W    = (const float*)d_in[2];
    const float* R    = (const float*)d_in[3];
    const float* bias = (const float*)d_in[4];
    float* out = (float*)d_out;

    dim3 grid(1024);   // (8192/128) * (1024/64)
    dim3 block(256);
    hipLaunchKernelGGL(gru_fused_kernel, grid, block, 0, stream, X, H, W, R, bias, out);
}

// Round 2
// 247.678 us; speedup vs baseline: 2.0619x; 2.0619x over previous
//
#include <hip/hip_runtime.h>
#include <math.h>

typedef __attribute__((ext_vector_type(4))) float floatx4;
typedef __attribute__((ext_vector_type(8))) short shortx8;

#define M_TILE 128
#define N_TILE 64
#define BK 32

__device__ __forceinline__ unsigned short f2bf(float f) {
    union { float f; unsigned int u; } v; v.f = f;
    unsigned int r = v.u + 0x7fffu + ((v.u >> 16) & 1u);   // round-to-nearest-even
    return (unsigned short)(r >> 16);
}

__device__ __forceinline__ void gload_lds16(const unsigned short* g, unsigned short* l) {
    __builtin_amdgcn_global_load_lds(
        (const __attribute__((address_space(1))) void*)g,
        (__attribute__((address_space(3))) void*)l, 16, 0, 0);
}

// ---------------- preprocessing: fp32 -> bf16 ----------------
__global__ void cvt_kernel(const float* __restrict__ src, unsigned short* __restrict__ dst, int n4) {
    int i = blockIdx.x * blockDim.x + threadIdx.x;
    if (i >= n4) return;
    float4 v = ((const float4*)src)[i];
    ushort4 s;
    s.x = f2bf(v.x); s.y = f2bf(v.y); s.z = f2bf(v.z); s.w = f2bf(v.w);
    ((ushort4*)dst)[i] = s;
}

// src [1024][3072] fp32 -> dst [3072][1024] bf16 (transpose + convert)
__global__ void transpose_cvt_kernel(const float* __restrict__ src, unsigned short* __restrict__ dst) {
    __shared__ float t[32][33];
    const int nt = blockIdx.x;            // 0..95
    const int kt = blockIdx.y;            // 0..31
    const int tx = threadIdx.x;           // 0..31
    const int ty = threadIdx.y;           // 0..7
    #pragma unroll
    for (int i = 0; i < 4; ++i) {
        int k = kt * 32 + ty + i * 8;
        t[ty + i * 8][tx] = src[(size_t)k * 3072 + nt * 32 + tx];
    }
    __syncthreads();
    #pragma unroll
    for (int i = 0; i < 4; ++i) {
        int n = nt * 32 + ty + i * 8;
        dst[(size_t)n * 1024 + kt * 32 + tx] = f2bf(t[tx][ty + i * 8]);
    }
}

// ---------------- main fused GEMM kernel (bf16 inputs via d_ws) ----------------
__global__ __launch_bounds__(256, 2)
void gru_mfma_kernel(const unsigned short* __restrict__ Xb,   // [8192][1024] bf16
                     const unsigned short* __restrict__ Hb,   // [8192][1024] bf16
                     const unsigned short* __restrict__ Wt,   // [3072][1024] bf16 (W^T)
                     const unsigned short* __restrict__ Rt,   // [3072][1024] bf16 (R^T)
                     const float* __restrict__ H,             // fp32 h_tm1 (epilogue)
                     const float* __restrict__ bias,          // [2][3072]
                     float* __restrict__ out)
{
    // Unpadded [row][BK] bf16 tiles (required by global_load_lds lane mapping)
    __shared__ __attribute__((aligned(16))) unsigned short ldsA[2][M_TILE * BK]; // 16 KB
    __shared__ __attribute__((aligned(16))) unsigned short ldsW[6][N_TILE * BK]; // 24 KB

    const int tid  = threadIdx.x;
    const int bid  = blockIdx.x;
    const int bn   = bid & 15;        // XCD swizzle: same weight slice -> same XCD
    const int bm   = bid >> 4;
    const int m0   = bm * M_TILE;
    const int n0   = bn * N_TILE;

    const int wid  = tid >> 6;
    const int lane = tid & 63;
    const int wr   = wid >> 1;        // wave row (0..1): 64 rows each
    const int wc   = wid & 1;         // wave col (0..1): 32 cols each
    const int lo   = lane & 15;
    const int quad = lane >> 4;

    // per-lane staging coords: lane handles 16 B = 8 bf16
    const int srow = lane >> 2;       // row-within-16-row segment
    const int skof = (lane & 3) * 8;  // k offset

    floatx4 acc_z[4][2]  = {};
    floatx4 acc_r[4][2]  = {};
    floatx4 acc_xh[4][2] = {};
    floatx4 acc_rh[4][2] = {};

    for (int k0 = 0; k0 < 1024; k0 += BK) {
        // stage A tiles: X and H, 128x32 bf16 each; 2 rounds of 4 segments
        #pragma unroll
        for (int r = 0; r < 2; ++r) {
            const int seg = r * 4 + wid;                       // 0..7 -> 16 rows each
            const size_t gofs = (size_t)(m0 + seg * 16 + srow) * 1024 + k0 + skof;
            gload_lds16(Xb + gofs, &ldsA[0][seg * 512]);
            gload_lds16(Hb + gofs, &ldsA[1][seg * 512]);
        }
        // stage 6 weight tiles (64x32 bf16): wave wid takes segment wid
        #pragma unroll
        for (int g = 0; g < 6; ++g) {
            const unsigned short* base = (g < 3) ? Wt : Rt;
            const int gm = (g < 3) ? g : g - 3;
            const size_t gofs = (size_t)(gm * 1024 + n0 + wid * 16 + srow) * 1024 + k0 + skof;
            gload_lds16(base + gofs, &ldsW[g][wid * 512]);
        }
        __syncthreads();

        shortx8 a_in[4], a_h[4];
        #pragma unroll
        for (int i = 0; i < 4; ++i) {
            a_in[i] = *(const shortx8*)&ldsA[0][(wr * 64 + i * 16 + lo) * BK + quad * 8];
            a_h[i]  = *(const shortx8*)&ldsA[1][(wr * 64 + i * 16 + lo) * BK + quad * 8];
        }
        #pragma unroll
        for (int j = 0; j < 2; ++j) {
            const int nc = (wc * 32 + j * 16 + lo) * BK + quad * 8;
            shortx8 bz  = *(const shortx8*)&ldsW[0][nc];
            shortx8 bre = *(const shortx8*)&ldsW[1][nc];
            shortx8 bh  = *(const shortx8*)&ldsW[2][nc];
            shortx8 rz  = *(const shortx8*)&ldsW[3][nc];
            shortx8 rre = *(const shortx8*)&ldsW[4][nc];
            shortx8 rh  = *(const shortx8*)&ldsW[5][nc];
            #pragma unroll
            for (int i = 0; i < 4; ++i) {
                acc_z[i][j]  = __builtin_amdgcn_mfma_f32_16x16x32_bf16(a_in[i], bz,  acc_z[i][j],  0, 0, 0);
                acc_z[i][j]  = __builtin_amdgcn_mfma_f32_16x16x32_bf16(a_h[i],  rz,  acc_z[i][j],  0, 0, 0);
                acc_r[i][j]  = __builtin_amdgcn_mfma_f32_16x16x32_bf16(a_in[i], bre, acc_r[i][j],  0, 0, 0);
                acc_r[i][j]  = __builtin_amdgcn_mfma_f32_16x16x32_bf16(a_h[i],  rre, acc_r[i][j],  0, 0, 0);
                acc_xh[i][j] = __builtin_amdgcn_mfma_f32_16x16x32_bf16(a_in[i], bh,  acc_xh[i][j], 0, 0, 0);
                acc_rh[i][j] = __builtin_amdgcn_mfma_f32_16x16x32_bf16(a_h[i],  rh,  acc_rh[i][j], 0, 0, 0);
            }
        }
        __syncthreads();
    }

    // epilogue: bias + gates + blend
    #pragma unroll
    for (int j = 0; j < 2; ++j) {
        const int col = n0 + wc * 32 + j * 16 + lo;
        const float bz  = bias[col]        + bias[3072 + col];
        const float brr = bias[1024 + col] + bias[4096 + col];
        const float b0h = bias[2048 + col];
        const float b1h = bias[5120 + col];
        #pragma unroll
        for (int i = 0; i < 4; ++i) {
            const int rowb = m0 + wr * 64 + i * 16 + quad * 4;
            #pragma unroll
            for (int r = 0; r < 4; ++r) {
                const int row = rowb + r;
                float sz = acc_z[i][j][r]  + bz;
                float sr = acc_r[i][j][r]  + brr;
                float xh = acc_xh[i][j][r] + b0h;
                float rh = acc_rh[i][j][r] + b1h;
                float z   = fminf(fmaxf(0.2f * sz + 0.5f, 0.0f), 1.0f);
                float rr2 = fminf(fmaxf(0.2f * sr + 0.5f, 0.0f), 1.0f);
                float pre = xh + rr2 * rh;
                float e   = __expf(2.0f * pre);
                float th  = 1.0f - 2.0f / (e + 1.0f);
                float hp  = H[(size_t)row * 1024 + col];
                out[(size_t)row * 1024 + col] = z * hp + (1.0f - z) * th;
            }
        }
    }
}

// ---------------- fallback (round-1, fp32 inline-convert) ----------------
#define KP 40
__global__ __launch_bounds__(256, 2)
void gru_fused_kernel(const float* __restrict__ X, const float* __restrict__ H,
                      const float* __restrict__ W, const float* __restrict__ R,
                      const float* __restrict__ bias, float* __restrict__ out)
{
    __shared__ __attribute__((aligned(16))) unsigned short ldsA[2][M_TILE * KP];
    __shared__ __attribute__((aligned(16))) unsigned short ldsW[6][N_TILE * KP];
    const int tid = threadIdx.x, bid = blockIdx.x;
    const int bn = bid & 15, bm = bid >> 4;
    const int m0 = bm * M_TILE, n0 = bn * N_TILE;
    const int wid = tid >> 6, lane = tid & 63;
    const int wr = wid >> 1, wc = wid & 1;
    const int lo = lane & 15, quad = lane >> 4;
    floatx4 acc_z[4][2] = {}, acc_r[4][2] = {}, acc_xh[4][2] = {}, acc_rh[4][2] = {};
    for (int k0 = 0; k0 < 1024; k0 += BK) {
        #pragma unroll
        for (int i = 0; i < 8; ++i) {
            int idx = tid + i * 256;
            const float* base = (idx < 1024) ? X : H;
            int rem = idx & 1023, row = rem >> 3, kq = rem & 7;
            const float4 v = *(const float4*)(base + (size_t)(m0 + row) * 1024 + k0 + kq * 4);
            ushort4 s; s.x = f2bf(v.x); s.y = f2bf(v.y); s.z = f2bf(v.z); s.w = f2bf(v.w);
            *(ushort4*)&ldsA[idx >> 10][row * KP + kq * 4] = s;
        }
        #pragma unroll
        for (int i = 0; i < 3; ++i) {
            int b = tid + i * 256, g = b >> 7, rem = b & 127, kb = rem >> 4, c4 = rem & 15;
            const float* wb = (g < 3) ? W : R;
            int gm = (g < 3) ? g : g - 3;
            const float* src = wb + (size_t)(k0 + kb * 4) * 3072 + gm * 1024 + n0 + c4 * 4;
            float4 r0 = *(const float4*)(src);
            float4 r1 = *(const float4*)(src + 3072);
            float4 r2 = *(const float4*)(src + 2 * 3072);
            float4 r3 = *(const float4*)(src + 3 * 3072);
            ushort4 s0, s1, s2, s3;
            s0.x=f2bf(r0.x); s0.y=f2bf(r1.x); s0.z=f2bf(r2.x); s0.w=f2bf(r3.x);
            s1.x=f2bf(r0.y); s1.y=f2bf(r1.y); s1.z=f2bf(r2.y); s1.w=f2bf(r3.y);
            s2.x=f2bf(r0.z); s2.y=f2bf(r1.z); s2.z=f2bf(r2.z); s2.w=f2bf(r3.z);
            s3.x=f2bf(r0.w); s3.y=f2bf(r1.w); s3.z=f2bf(r2.w); s3.w=f2bf(r3.w);
            unsigned short* dst = &ldsW[g][0];
            *(ushort4*)&dst[(c4*4+0)*KP + kb*4] = s0;
            *(ushort4*)&dst[(c4*4+1)*KP + kb*4] = s1;
            *(ushort4*)&dst[(c4*4+2)*KP + kb*4] = s2;
            *(ushort4*)&dst[(c4*4+3)*KP + kb*4] = s3;
        }
        __syncthreads();
        shortx8 a_in[4], a_h[4];
        #pragma unroll
        for (int i = 0; i < 4; ++i) {
            a_in[i] = *(const shortx8*)&ldsA[0][(wr*64 + i*16 + lo) * KP + quad*8];
            a_h[i]  = *(const shortx8*)&ldsA[1][(wr*64 + i*16 + lo) * KP + quad*8];
        }
        #pragma unroll
        for (int j = 0; j < 2; ++j) {
            const int nc = (wc*32 + j*16 + lo) * KP + quad*8;
            shortx8 bz  = *(const shortx8*)&ldsW[0][nc];
            shortx8 bre = *(const shortx8*)&ldsW[1][nc];
            shortx8 bh  = *(const shortx8*)&ldsW[2][nc];
            shortx8 rz  = *(const shortx8*)&ldsW[3][nc];
            shortx8 rre = *(const shortx8*)&ldsW[4][nc];
            shortx8 rh  = *(const shortx8*)&ldsW[5][nc];
            #pragma unroll
            for (int i = 0; i < 4; ++i) {
                acc_z[i][j]  = __builtin_amdgcn_mfma_f32_16x16x32_bf16(a_in[i], bz,  acc_z[i][j],  0, 0, 0);
                acc_z[i][j]  = __builtin_amdgcn_mfma_f32_16x16x32_bf16(a_h[i],  rz,  acc_z[i][j],  0, 0, 0);
                acc_r[i][j]  = __builtin_amdgcn_mfma_f32_16x16x32_bf16(a_in[i], bre, acc_r[i][j],  0, 0, 0);
                acc_r[i][j]  = __builtin_amdgcn_mfma_f32_16x16x32_bf16(a_h[i],  rre, acc_r[i][j],  0, 0, 0);
                acc_xh[i][j] = __builtin_amdgcn_mfma_f32_16x16x32_bf16(a_in[i], bh,  acc_xh[i][j], 0, 0, 0);
                acc_rh[i][j] = __builtin_amdgcn_mfma_f32_16x16x32_bf16(a_h[i],  rh,  acc_rh[i][j], 0, 0, 0);
            }
        }
        __syncthreads();
    }
    #pragma unroll
    for (int j = 0; j < 2; ++j) {
        const int col = n0 + wc*32 + j*16 + lo;
        const float bz  = bias[col]        + bias[3072 + col];
        const float brr = bias[1024 + col] + bias[4096 + col];
        const float b0h = bias[2048 + col];
        const float b1h = bias[5120 + col];
        #pragma unroll
        for (int i = 0; i < 4; ++i) {
            const int rowb = m0 + wr*64 + i*16 + quad*4;
            #pragma unroll
            for (int r = 0; r < 4; ++r) {
                const int row = rowb + r;
                float sz = acc_z[i][j][r]  + bz;
                float sr = acc_r[i][j][r]  + brr;
                float xh = acc_xh[i][j][r] + b0h;
                float rh = acc_rh[i][j][r] + b1h;
                float z   = fminf(fmaxf(0.2f * sz + 0.5f, 0.0f), 1.0f);
                float rr2 = fminf(fmaxf(0.2f * sr + 0.5f, 0.0f), 1.0f);
                float pre = xh + rr2 * rh;
                float e   = __expf(2.0f * pre);
                float th  = 1.0f - 2.0f / (e + 1.0f);
                float hp  = H[(size_t)row * 1024 + col];
                out[(size_t)row * 1024 + col] = z * hp + (1.0f - z) * th;
            }
        }
    }
}

extern "C" void kernel_launch(void* const* d_in, const int* in_sizes, int n_in,
                              void* d_out, int out_size, void* d_ws, size_t ws_size,
                              hipStream_t stream)
{
    const float* X    = (const float*)d_in[0];
    const float* H    = (const float*)d_in[1];
    const float* W    = (const float*)d_in[2];
    const float* R    = (const float*)d_in[3];
    const float* bias = (const float*)d_in[4];
    float* out = (float*)d_out;

    const size_t need = (size_t)(8192 * 1024) * 2 * 2 + (size_t)(3072 * 1024) * 2 * 2; // 46.1 MB
    if (ws_size >= need) {
        unsigned short* Xb = (unsigned short*)d_ws;
        unsigned short* Hb = Xb + (size_t)8192 * 1024;
        unsigned short* Wt = Hb + (size_t)8192 * 1024;
        unsigned short* Rt = Wt + (size_t)3072 * 1024;
        hipLaunchKernelGGL(cvt_kernel, dim3(8192), dim3(256), 0, stream, X, Xb, 2097152);
        hipLaunchKernelGGL(cvt_kernel, dim3(8192), dim3(256), 0, stream, H, Hb, 2097152);
        hipLaunchKernelGGL(transpose_cvt_kernel, dim3(96, 32), dim3(32, 8), 0, stream, W, Wt);
        hipLaunchKernelGGL(transpose_cvt_kernel, dim3(96, 32), dim3(32, 8), 0, stream, R, Rt);
        hipLaunchKernelGGL(gru_mfma_kernel, dim3(1024), dim3(256), 0, stream,
                           Xb, Hb, Wt, Rt, H, bias, out);
    } else {
        hipLaunchKernelGGL(gru_fused_kernel, dim3(1024), dim3(256), 0, stream, X, H, W, R, bias, out);
    }
}

// Round 5
// 237.816 us; speedup vs baseline: 2.1474x; 1.0415x over previous
//
#include <hip/hip_runtime.h>
#include <math.h>

typedef __attribute__((ext_vector_type(4))) float floatx4;
typedef __attribute__((ext_vector_type(8))) short shortx8;

#define M_TILE 128
#define N_TILE 64
#define BK 64

__device__ __forceinline__ unsigned short f2bf(float f) {
    union { float f; unsigned int u; } v; v.f = f;
    unsigned int r = v.u + 0x7fffu + ((v.u >> 16) & 1u);   // RNE
    return (unsigned short)(r >> 16);
}
__device__ __forceinline__ void gload_lds16(const unsigned short* g, unsigned short* l) {
    __builtin_amdgcn_global_load_lds(
        (const __attribute__((address_space(1))) void*)g,
        (__attribute__((address_space(3))) void*)l, 16, 0, 0);
}

// ---------- single preprocessing kernel: cvt X,H + transpose-cvt W,R ----------
// blocks [0,16384): cvt (first half X, second half H), 1024 floats/block
// blocks [16384, 16384+1536): 64k x 64n transpose tiles (first 768 W, then R)
__global__ void prep_kernel(const float* __restrict__ X, const float* __restrict__ H,
                            const float* __restrict__ W, const float* __restrict__ R,
                            unsigned short* __restrict__ Xb, unsigned short* __restrict__ Hb,
                            unsigned short* __restrict__ Wt, unsigned short* __restrict__ Rt)
{
    const int bid = blockIdx.x;
    const int tx  = threadIdx.x;
    if (bid < 16384) {
        const float* src = (bid < 8192) ? X : H;
        unsigned short* dst = (bid < 8192) ? Xb : Hb;
        const int i = (bid & 8191) * 256 + tx;         // float4 index (8192 IS pow2)
        float4 v = ((const float4*)src)[i];
        ushort4 s;
        s.x = f2bf(v.x); s.y = f2bf(v.y); s.z = f2bf(v.z); s.w = f2bf(v.w);
        ((ushort4*)dst)[i] = s;
        return;
    }
    __shared__ float tile[64][66];
    const int tb = bid - 16384;
    const float* src = (tb < 768) ? W : R;
    unsigned short* dst = (tb < 768) ? Wt : Rt;
    const int tt = (tb < 768) ? tb : tb - 768;         // FIX: 768 is not pow2, & 767 was wrong
    const int col0 = (tt % 48) * 64;
    const int k0   = (tt / 48) * 64;
    const int n4 = tx & 15, kl = tx >> 4;
    #pragma unroll
    for (int i = 0; i < 4; ++i) {
        const int k = kl + i * 16;
        float4 v = *(const float4*)(src + (size_t)(k0 + k) * 3072 + col0 + n4 * 4);
        tile[k][n4 * 4 + 0] = v.x; tile[k][n4 * 4 + 1] = v.y;
        tile[k][n4 * 4 + 2] = v.z; tile[k][n4 * 4 + 3] = v.w;
    }
    __syncthreads();
    #pragma unroll
    for (int i = 0; i < 2; ++i) {
        const int c  = tx + i * 256;
        const int nl = c >> 3, kc = c & 7;
        ushort4 s0, s1;
        s0.x = f2bf(tile[kc*8+0][nl]); s0.y = f2bf(tile[kc*8+1][nl]);
        s0.z = f2bf(tile[kc*8+2][nl]); s0.w = f2bf(tile[kc*8+3][nl]);
        s1.x = f2bf(tile[kc*8+4][nl]); s1.y = f2bf(tile[kc*8+5][nl]);
        s1.z = f2bf(tile[kc*8+6][nl]); s1.w = f2bf(tile[kc*8+7][nl]);
        unsigned short* p = dst + (size_t)(col0 + nl) * 1024 + k0 + kc * 8;
        *(ushort4*)p = s0;
        *(ushort4*)(p + 4) = s1;
    }
}

// ---------------- main fused GEMM kernel (BK=64, monotone staging) ----------------
__global__ __launch_bounds__(256, 2)
void gru_mfma_kernel(const unsigned short* __restrict__ Xb,   // [8192][1024] bf16
                     const unsigned short* __restrict__ Hb,   // [8192][1024] bf16
                     const unsigned short* __restrict__ Wt,   // [3072][1024] bf16 (W^T)
                     const unsigned short* __restrict__ Rt,   // [3072][1024] bf16 (R^T)
                     const float* __restrict__ H,             // fp32 h_tm1 (epilogue)
                     const float* __restrict__ bias,          // [2][3072]
                     float* __restrict__ out)
{
    __shared__ __attribute__((aligned(16))) unsigned short ldsA[2][M_TILE * BK]; // 32 KB
    __shared__ __attribute__((aligned(16))) unsigned short ldsW[6][N_TILE * BK]; // 48 KB

    const int tid  = threadIdx.x;
    const int bid  = blockIdx.x;
    const int bn   = bid & 15;        // XCD swizzle
    const int bm   = bid >> 4;
    const int m0   = bm * M_TILE;
    const int n0   = bn * N_TILE;

    const int wid  = tid >> 6;
    const int lane = tid & 63;
    const int wr   = wid >> 1;
    const int wc   = wid & 1;
    const int lo   = lane & 15;
    const int quad = lane >> 4;

    // staging: 8-row segments of 64 k; lane order == address order (monotone)
    const int srow = lane >> 3;       // row within segment
    const int skof = (lane & 7) * 8;  // k offset

    floatx4 acc_z[4][2]  = {};
    floatx4 acc_r[4][2]  = {};
    floatx4 acc_xh[4][2] = {};
    floatx4 acc_rh[4][2] = {};

    for (int k0 = 0; k0 < 1024; k0 += BK) {
        // A tiles: 2 arrays x 16 segments of 8 rows
        #pragma unroll
        for (int r = 0; r < 8; ++r) {
            const int seg = r * 4 + wid;               // 0..31
            const int arr = seg >> 4;
            const int s   = seg & 15;
            const size_t gofs = (size_t)(m0 + s * 8 + srow) * 1024 + k0 + skof;
            gload_lds16(((arr == 0) ? Xb : Hb) + gofs, &ldsA[arr][s * 512]);
        }
        // weights: 6 tiles x 8 segments of 8 rows
        #pragma unroll
        for (int r = 0; r < 12; ++r) {
            const int seg = r * 4 + wid;               // 0..47
            const int g   = seg >> 3;
            const int s   = seg & 7;
            const unsigned short* base = (g < 3) ? Wt : Rt;
            const int gm = (g < 3) ? g : g - 3;
            const size_t gofs = (size_t)(gm * 1024 + n0 + s * 8 + srow) * 1024 + k0 + skof;
            gload_lds16(base + gofs, &ldsW[g][s * 512]);
        }
        __syncthreads();

        #pragma unroll
        for (int ks = 0; ks < 2; ++ks) {
            const int kcp = (ks * 4 + quad) * 8;
            shortx8 a_in[4], a_h[4];
            #pragma unroll
            for (int i = 0; i < 4; ++i) {
                const int row = wr * 64 + i * 16 + lo;
                a_in[i] = *(const shortx8*)&ldsA[0][row * BK + kcp];
                a_h[i]  = *(const shortx8*)&ldsA[1][row * BK + kcp];
            }
            #pragma unroll
            for (int j = 0; j < 2; ++j) {
                const int nc = (wc * 32 + j * 16 + lo) * BK + kcp;
                shortx8 bz  = *(const shortx8*)&ldsW[0][nc];
                shortx8 bre = *(const shortx8*)&ldsW[1][nc];
                shortx8 bh  = *(const shortx8*)&ldsW[2][nc];
                shortx8 rz  = *(const shortx8*)&ldsW[3][nc];
                shortx8 rre = *(const shortx8*)&ldsW[4][nc];
                shortx8 rh  = *(const shortx8*)&ldsW[5][nc];
                #pragma unroll
                for (int i = 0; i < 4; ++i) {
                    acc_z[i][j]  = __builtin_amdgcn_mfma_f32_16x16x32_bf16(a_in[i], bz,  acc_z[i][j],  0, 0, 0);
                    acc_z[i][j]  = __builtin_amdgcn_mfma_f32_16x16x32_bf16(a_h[i],  rz,  acc_z[i][j],  0, 0, 0);
                    acc_r[i][j]  = __builtin_amdgcn_mfma_f32_16x16x32_bf16(a_in[i], bre, acc_r[i][j],  0, 0, 0);
                    acc_r[i][j]  = __builtin_amdgcn_mfma_f32_16x16x32_bf16(a_h[i],  rre, acc_r[i][j],  0, 0, 0);
                    acc_xh[i][j] = __builtin_amdgcn_mfma_f32_16x16x32_bf16(a_in[i], bh,  acc_xh[i][j], 0, 0, 0);
                    acc_rh[i][j] = __builtin_amdgcn_mfma_f32_16x16x32_bf16(a_h[i],  rh,  acc_rh[i][j], 0, 0, 0);
                }
            }
        }
        __syncthreads();
    }

    // epilogue (identical to round-2 passing version)
    #pragma unroll
    for (int j = 0; j < 2; ++j) {
        const int col = n0 + wc * 32 + j * 16 + lo;
        const float bz  = bias[col]        + bias[3072 + col];
        const float brr = bias[1024 + col] + bias[4096 + col];
        const float b0h = bias[2048 + col];
        const float b1h = bias[5120 + col];
        #pragma unroll
        for (int i = 0; i < 4; ++i) {
            const int rowb = m0 + wr * 64 + i * 16 + quad * 4;
            #pragma unroll
            for (int r = 0; r < 4; ++r) {
                const int row = rowb + r;
                float sz = acc_z[i][j][r]  + bz;
                float sr = acc_r[i][j][r]  + brr;
                float xh = acc_xh[i][j][r] + b0h;
                float rh = acc_rh[i][j][r] + b1h;
                float z   = fminf(fmaxf(0.2f * sz + 0.5f, 0.0f), 1.0f);
                float rr2 = fminf(fmaxf(0.2f * sr + 0.5f, 0.0f), 1.0f);
                float pre = xh + rr2 * rh;
                float e   = __expf(2.0f * pre);
                float th  = 1.0f - 2.0f / (e + 1.0f);
                float hp  = H[(size_t)row * 1024 + col];
                out[(size_t)row * 1024 + col] = z * hp + (1.0f - z) * th;
            }
        }
    }
}

// ---------------- fallback (round-1, fp32 inline-convert) ----------------
#define KP 40
#define FBK 32
__global__ __launch_bounds__(256, 2)
void gru_fused_kernel(const float* __restrict__ X, const float* __restrict__ H,
                      const float* __restrict__ W, const float* __restrict__ R,
                      const float* __restrict__ bias, float* __restrict__ out)
{
    __shared__ __attribute__((aligned(16))) unsigned short ldsA[2][M_TILE * KP];
    __shared__ __attribute__((aligned(16))) unsigned short ldsW[6][N_TILE * KP];
    const int tid = threadIdx.x, bid = blockIdx.x;
    const int bn = bid & 15, bm = bid >> 4;
    const int m0 = bm * M_TILE, n0 = bn * N_TILE;
    const int wid = tid >> 6, lane = tid & 63;
    const int wr = wid >> 1, wc = wid & 1;
    const int lo = lane & 15, quad = lane >> 4;
    floatx4 acc_z[4][2] = {}, acc_r[4][2] = {}, acc_xh[4][2] = {}, acc_rh[4][2] = {};
    for (int k0 = 0; k0 < 1024; k0 += FBK) {
        #pragma unroll
        for (int i = 0; i < 8; ++i) {
            int idx = tid + i * 256;
            const float* base = (idx < 1024) ? X : H;
            int rem = idx & 1023, row = rem >> 3, kq = rem & 7;
            const float4 v = *(const float4*)(base + (size_t)(m0 + row) * 1024 + k0 + kq * 4);
            ushort4 s; s.x = f2bf(v.x); s.y = f2bf(v.y); s.z = f2bf(v.z); s.w = f2bf(v.w);
            *(ushort4*)&ldsA[idx >> 10][row * KP + kq * 4] = s;
        }
        #pragma unroll
        for (int i = 0; i < 3; ++i) {
            int b = tid + i * 256, g = b >> 7, rem = b & 127, kb = rem >> 4, c4 = rem & 15;
            const float* wb = (g < 3) ? W : R;
            int gm = (g < 3) ? g : g - 3;
            const float* src = wb + (size_t)(k0 + kb * 4) * 3072 + gm * 1024 + n0 + c4 * 4;
            float4 r0 = *(const float4*)(src);
            float4 r1 = *(const float4*)(src + 3072);
            float4 r2 = *(const float4*)(src + 2 * 3072);
            float4 r3 = *(const float4*)(src + 3 * 3072);
            ushort4 s0, s1, s2, s3;
            s0.x=f2bf(r0.x); s0.y=f2bf(r1.x); s0.z=f2bf(r2.x); s0.w=f2bf(r3.x);
            s1.x=f2bf(r0.y); s1.y=f2bf(r1.y); s1.z=f2bf(r2.y); s1.w=f2bf(r3.y);
            s2.x=f2bf(r0.z); s2.y=f2bf(r1.z); s2.z=f2bf(r2.z); s2.w=f2bf(r3.z);
            s3.x=f2bf(r0.w); s3.y=f2bf(r1.w); s3.z=f2bf(r2.w); s3.w=f2bf(r3.w);
            unsigned short* dst = &ldsW[g][0];
            *(ushort4*)&dst[(c4*4+0)*KP + kb*4] = s0;
            *(ushort4*)&dst[(c4*4+1)*KP + kb*4] = s1;
            *(ushort4*)&dst[(c4*4+2)*KP + kb*4] = s2;
            *(ushort4*)&dst[(c4*4+3)*KP + kb*4] = s3;
        }
        __syncthreads();
        shortx8 a_in[4], a_h[4];
        #pragma unroll
        for (int i = 0; i < 4; ++i) {
            a_in[i] = *(const shortx8*)&ldsA[0][(wr*64 + i*16 + lo) * KP + quad*8];
            a_h[i]  = *(const shortx8*)&ldsA[1][(wr*64 + i*16 + lo) * KP + quad*8];
        }
        #pragma unroll
        for (int j = 0; j < 2; ++j) {
            const int nc = (wc*32 + j*16 + lo) * KP + quad*8;
            shortx8 bz  = *(const shortx8*)&ldsW[0][nc];
            shortx8 bre = *(const shortx8*)&ldsW[1][nc];
            shortx8 bh  = *(const shortx8*)&ldsW[2][nc];
            shortx8 rz  = *(const shortx8*)&ldsW[3][nc];
            shortx8 rre = *(const shortx8*)&ldsW[4][nc];
            shortx8 rh  = *(const shortx8*)&ldsW[5][nc];
            #pragma unroll
            for (int i = 0; i < 4; ++i) {
                acc_z[i][j]  = __builtin_amdgcn_mfma_f32_16x16x32_bf16(a_in[i], bz,  acc_z[i][j],  0, 0, 0);
                acc_z[i][j]  = __builtin_amdgcn_mfma_f32_16x16x32_bf16(a_h[i],  rz,  acc_z[i][j],  0, 0, 0);
                acc_r[i][j]  = __builtin_amdgcn_mfma_f32_16x16x32_bf16(a_in[i], bre, acc_r[i][j],  0, 0, 0);
                acc_r[i][j]  = __builtin_amdgcn_mfma_f32_16x16x32_bf16(a_h[i],  rre, acc_r[i][j],  0, 0, 0);
                acc_xh[i][j] = __builtin_amdgcn_mfma_f32_16x16x32_bf16(a_in[i], bh,  acc_xh[i][j], 0, 0, 0);
                acc_rh[i][j] = __builtin_amdgcn_mfma_f32_16x16x32_bf16(a_h[i],  rh,  acc_rh[i][j], 0, 0, 0);
            }
        }
        __syncthreads();
    }
    #pragma unroll
    for (int j = 0; j < 2; ++j) {
        const int col = n0 + wc*32 + j*16 + lo;
        const float bz  = bias[col]        + bias[3072 + col];
        const float brr = bias[1024 + col] + bias[4096 + col];
        const float b0h = bias[2048 + col];
        const float b1h = bias[5120 + col];
        #pragma unroll
        for (int i = 0; i < 4; ++i) {
            const int rowb = m0 + wr*64 + i*16 + quad*4;
            #pragma unroll
            for (int r = 0; r < 4; ++r) {
                const int row = rowb + r;
                float sz = acc_z[i][j][r]  + bz;
                float sr = acc_r[i][j][r]  + brr;
                float xh = acc_xh[i][j][r] + b0h;
                float rh = acc_rh[i][j][r] + b1h;
                float z   = fminf(fmaxf(0.2f * sz + 0.5f, 0.0f), 1.0f);
                float rr2 = fminf(fmaxf(0.2f * sr + 0.5f, 0.0f), 1.0f);
                float pre = xh + rr2 * rh;
                float e   = __expf(2.0f * pre);
                float th  = 1.0f - 2.0f / (e + 1.0f);
                float hp  = H[(size_t)row * 1024 + col];
                out[(size_t)row * 1024 + col] = z * hp + (1.0f - z) * th;
            }
        }
    }
}

extern "C" void kernel_launch(void* const* d_in, const int* in_sizes, int n_in,
                              void* d_out, int out_size, void* d_ws, size_t ws_size,
                              hipStream_t stream)
{
    const float* X    = (const float*)d_in[0];
    const float* H    = (const float*)d_in[1];
    const float* W    = (const float*)d_in[2];
    const float* R    = (const float*)d_in[3];
    const float* bias = (const float*)d_in[4];
    float* out = (float*)d_out;

    const size_t need = (size_t)(8192 * 1024) * 2 * 2 + (size_t)(3072 * 1024) * 2 * 2; // 46.1 MB
    if (ws_size >= need) {
        unsigned short* Xb = (unsigned short*)d_ws;
        unsigned short* Hb = Xb + (size_t)8192 * 1024;
        unsigned short* Wt = Hb + (size_t)8192 * 1024;
        unsigned short* Rt = Wt + (size_t)3072 * 1024;
        hipLaunchKernelGGL(prep_kernel, dim3(16384 + 1536), dim3(256), 0, stream,
                           X, H, W, R, Xb, Hb, Wt, Rt);
        hipLaunchKernelGGL(gru_mfma_kernel, dim3(1024), dim3(256), 0, stream,
                           Xb, Hb, Wt, Rt, H, bias, out);
    } else {
        hipLaunchKernelGGL(gru_fused_kernel, dim3(1024), dim3(256), 0, stream, X, H, W, R, bias, out);
    }
}

// Round 6
// 228.583 us; speedup vs baseline: 2.2342x; 1.0404x over previous
//
#include <hip/hip_runtime.h>
#include <math.h>

typedef __attribute__((ext_vector_type(4))) float floatx4;
typedef __attribute__((ext_vector_type(8))) short shortx8;

#define M_TILE 128
#define N_TILE 64
#define BK 64

__device__ __forceinline__ unsigned short f2bf(float f) {
    union { float f; unsigned int u; } v; v.f = f;
    unsigned int r = v.u + 0x7fffu + ((v.u >> 16) & 1u);   // RNE
    return (unsigned short)(r >> 16);
}
__device__ __forceinline__ float bf2f(unsigned short u) {
    union { unsigned int u; float f; } v; v.u = ((unsigned int)u) << 16;
    return v.f;
}
__device__ __forceinline__ void gload_lds16(const unsigned short* g, unsigned short* l) {
    __builtin_amdgcn_global_load_lds(
        (const __attribute__((address_space(1))) void*)g,
        (__attribute__((address_space(3))) void*)l, 16, 0, 0);
}

// ---------- single preprocessing kernel: cvt X,H + transpose-cvt W,R ----------
__global__ void prep_kernel(const float* __restrict__ X, const float* __restrict__ H,
                            const float* __restrict__ W, const float* __restrict__ R,
                            unsigned short* __restrict__ Xb, unsigned short* __restrict__ Hb,
                            unsigned short* __restrict__ Wt, unsigned short* __restrict__ Rt)
{
    const int bid = blockIdx.x;
    const int tx  = threadIdx.x;
    if (bid < 16384) {
        const float* src = (bid < 8192) ? X : H;
        unsigned short* dst = (bid < 8192) ? Xb : Hb;
        const int i = (bid & 8191) * 256 + tx;         // float4 index (8192 IS pow2)
        float4 v = ((const float4*)src)[i];
        ushort4 s;
        s.x = f2bf(v.x); s.y = f2bf(v.y); s.z = f2bf(v.z); s.w = f2bf(v.w);
        ((ushort4*)dst)[i] = s;
        return;
    }
    __shared__ float tile[64][66];
    const int tb = bid - 16384;
    const float* src = (tb < 768) ? W : R;
    unsigned short* dst = (tb < 768) ? Wt : Rt;
    const int tt = (tb < 768) ? tb : tb - 768;         // 768 is not pow2 — no masking!
    const int col0 = (tt % 48) * 64;
    const int k0   = (tt / 48) * 64;
    const int n4 = tx & 15, kl = tx >> 4;
    #pragma unroll
    for (int i = 0; i < 4; ++i) {
        const int k = kl + i * 16;
        float4 v = *(const float4*)(src + (size_t)(k0 + k) * 3072 + col0 + n4 * 4);
        tile[k][n4 * 4 + 0] = v.x; tile[k][n4 * 4 + 1] = v.y;
        tile[k][n4 * 4 + 2] = v.z; tile[k][n4 * 4 + 3] = v.w;
    }
    __syncthreads();
    #pragma unroll
    for (int i = 0; i < 2; ++i) {
        const int c  = tx + i * 256;
        const int nl = c >> 3, kc = c & 7;
        ushort4 s0, s1;
        s0.x = f2bf(tile[kc*8+0][nl]); s0.y = f2bf(tile[kc*8+1][nl]);
        s0.z = f2bf(tile[kc*8+2][nl]); s0.w = f2bf(tile[kc*8+3][nl]);
        s1.x = f2bf(tile[kc*8+4][nl]); s1.y = f2bf(tile[kc*8+5][nl]);
        s1.z = f2bf(tile[kc*8+6][nl]); s1.w = f2bf(tile[kc*8+7][nl]);
        unsigned short* p = dst + (size_t)(col0 + nl) * 1024 + k0 + kc * 8;
        *(ushort4*)p = s0;
        *(ushort4*)(p + 4) = s1;
    }
}

// ---------------- main fused GEMM kernel (BK=64 + XOR bank swizzle) ----------------
// LDS layout: [row][64] bf16 in 8-elem chunks; physical chunk p at row r holds
// logical chunk p^(r&7).  global_load_lds deposits lane l at base+l*16 regardless
// of address order (HW-verified: rounds 3/4 bit-identical), so the staging lane
// fetches logical chunk (lane&7)^(row&7) and the frag read XORs it back.
__global__ __launch_bounds__(256, 2)
void gru_mfma_kernel(const unsigned short* __restrict__ Xb,   // [8192][1024] bf16
                     const unsigned short* __restrict__ Hb,   // [8192][1024] bf16
                     const unsigned short* __restrict__ Wt,   // [3072][1024] bf16 (W^T)
                     const unsigned short* __restrict__ Rt,   // [3072][1024] bf16 (R^T)
                     const float* __restrict__ bias,          // [2][3072]
                     float* __restrict__ out)
{
    __shared__ __attribute__((aligned(16))) unsigned short ldsA[2][M_TILE * BK]; // 32 KB
    __shared__ __attribute__((aligned(16))) unsigned short ldsW[6][N_TILE * BK]; // 48 KB

    const int tid  = threadIdx.x;
    const int bid  = blockIdx.x;
    const int bn   = bid & 15;        // XCD swizzle
    const int bm   = bid >> 4;
    const int m0   = bm * M_TILE;
    const int n0   = bn * N_TILE;

    const int wid  = tid >> 6;
    const int lane = tid & 63;
    const int wr   = wid >> 1;
    const int wc   = wid & 1;
    const int lo   = lane & 15;
    const int quad = lane >> 4;
    const int lx   = lane & 7;        // row&7 of every frag row this lane touches

    // staging: 8-row segments; lane covers row lrow, fetches XOR-permuted chunk
    const int lrow = lane >> 3;
    const int lkc  = (lane & 7) ^ lrow;

    floatx4 acc_z[4][2]  = {};
    floatx4 acc_r[4][2]  = {};
    floatx4 acc_xh[4][2] = {};
    floatx4 acc_rh[4][2] = {};

    for (int k0 = 0; k0 < 1024; k0 += BK) {
        // A tiles: 2 arrays x 16 segments of 8 rows
        #pragma unroll
        for (int r = 0; r < 8; ++r) {
            const int seg = r * 4 + wid;               // 0..31
            const int arr = seg >> 4;
            const int s   = seg & 15;
            const size_t gofs = (size_t)(m0 + s * 8 + lrow) * 1024 + k0 + lkc * 8;
            gload_lds16(((arr == 0) ? Xb : Hb) + gofs, &ldsA[arr][s * 512]);
        }
        // weights: 6 tiles x 8 segments of 8 rows
        #pragma unroll
        for (int r = 0; r < 12; ++r) {
            const int seg = r * 4 + wid;               // 0..47
            const int g   = seg >> 3;
            const int s   = seg & 7;
            const unsigned short* base = (g < 3) ? Wt : Rt;
            const int gm = (g < 3) ? g : g - 3;
            const size_t gofs = (size_t)(gm * 1024 + n0 + s * 8 + lrow) * 1024 + k0 + lkc * 8;
            gload_lds16(base + gofs, &ldsW[g][s * 512]);
        }
        __syncthreads();

        #pragma unroll
        for (int ks = 0; ks < 2; ++ks) {
            const int kcp = ((ks * 4 + quad) ^ lx) * 8;    // un-XOR the swizzle
            shortx8 a_in[4], a_h[4];
            #pragma unroll
            for (int i = 0; i < 4; ++i) {
                const int row = wr * 64 + i * 16 + lo;
                a_in[i] = *(const shortx8*)&ldsA[0][row * BK + kcp];
                a_h[i]  = *(const shortx8*)&ldsA[1][row * BK + kcp];
            }
            #pragma unroll
            for (int j = 0; j < 2; ++j) {
                const int nc = (wc * 32 + j * 16 + lo) * BK + kcp;
                shortx8 bz  = *(const shortx8*)&ldsW[0][nc];
                shortx8 bre = *(const shortx8*)&ldsW[1][nc];
                shortx8 bh  = *(const shortx8*)&ldsW[2][nc];
                shortx8 rz  = *(const shortx8*)&ldsW[3][nc];
                shortx8 rre = *(const shortx8*)&ldsW[4][nc];
                shortx8 rh  = *(const shortx8*)&ldsW[5][nc];
                #pragma unroll
                for (int i = 0; i < 4; ++i) {
                    acc_z[i][j]  = __builtin_amdgcn_mfma_f32_16x16x32_bf16(a_in[i], bz,  acc_z[i][j],  0, 0, 0);
                    acc_z[i][j]  = __builtin_amdgcn_mfma_f32_16x16x32_bf16(a_h[i],  rz,  acc_z[i][j],  0, 0, 0);
                    acc_r[i][j]  = __builtin_amdgcn_mfma_f32_16x16x32_bf16(a_in[i], bre, acc_r[i][j],  0, 0, 0);
                    acc_r[i][j]  = __builtin_amdgcn_mfma_f32_16x16x32_bf16(a_h[i],  rre, acc_r[i][j],  0, 0, 0);
                    acc_xh[i][j] = __builtin_amdgcn_mfma_f32_16x16x32_bf16(a_in[i], bh,  acc_xh[i][j], 0, 0, 0);
                    acc_rh[i][j] = __builtin_amdgcn_mfma_f32_16x16x32_bf16(a_h[i],  rh,  acc_rh[i][j], 0, 0, 0);
                }
            }
        }
        __syncthreads();
    }

    // epilogue: bias + gates + blend; h_tm1 re-read as bf16 (saves 32 MB fp32 fetch)
    #pragma unroll
    for (int j = 0; j < 2; ++j) {
        const int col = n0 + wc * 32 + j * 16 + lo;
        const float bz  = bias[col]        + bias[3072 + col];
        const float brr = bias[1024 + col] + bias[4096 + col];
        const float b0h = bias[2048 + col];
        const float b1h = bias[5120 + col];
        #pragma unroll
        for (int i = 0; i < 4; ++i) {
            const int rowb = m0 + wr * 64 + i * 16 + quad * 4;
            #pragma unroll
            for (int r = 0; r < 4; ++r) {
                const int row = rowb + r;
                float sz = acc_z[i][j][r]  + bz;
                float sr = acc_r[i][j][r]  + brr;
                float xh = acc_xh[i][j][r] + b0h;
                float rh = acc_rh[i][j][r] + b1h;
                float z   = fminf(fmaxf(0.2f * sz + 0.5f, 0.0f), 1.0f);
                float rr2 = fminf(fmaxf(0.2f * sr + 0.5f, 0.0f), 1.0f);
                float pre = xh + rr2 * rh;
                float e   = __expf(2.0f * pre);
                float th  = 1.0f - 2.0f / (e + 1.0f);
                float hp  = bf2f(Hb[(size_t)row * 1024 + col]);
                out[(size_t)row * 1024 + col] = z * hp + (1.0f - z) * th;
            }
        }
    }
}

// ---------------- fallback (round-1, fp32 inline-convert) ----------------
#define KP 40
#define FBK 32
__global__ __launch_bounds__(256, 2)
void gru_fused_kernel(const float* __restrict__ X, const float* __restrict__ H,
                      const float* __restrict__ W, const float* __restrict__ R,
                      const float* __restrict__ bias, float* __restrict__ out)
{
    __shared__ __attribute__((aligned(16))) unsigned short ldsA[2][M_TILE * KP];
    __shared__ __attribute__((aligned(16))) unsigned short ldsW[6][N_TILE * KP];
    const int tid = threadIdx.x, bid = blockIdx.x;
    const int bn = bid & 15, bm = bid >> 4;
    const int m0 = bm * M_TILE, n0 = bn * N_TILE;
    const int wid = tid >> 6, lane = tid & 63;
    const int wr = wid >> 1, wc = wid & 1;
    const int lo = lane & 15, quad = lane >> 4;
    floatx4 acc_z[4][2] = {}, acc_r[4][2] = {}, acc_xh[4][2] = {}, acc_rh[4][2] = {};
    for (int k0 = 0; k0 < 1024; k0 += FBK) {
        #pragma unroll
        for (int i = 0; i < 8; ++i) {
            int idx = tid + i * 256;
            const float* base = (idx < 1024) ? X : H;
            int rem = idx & 1023, row = rem >> 3, kq = rem & 7;
            const float4 v = *(const float4*)(base + (size_t)(m0 + row) * 1024 + k0 + kq * 4);
            ushort4 s; s.x = f2bf(v.x); s.y = f2bf(v.y); s.z = f2bf(v.z); s.w = f2bf(v.w);
            *(ushort4*)&ldsA[idx >> 10][row * KP + kq * 4] = s;
        }
        #pragma unroll
        for (int i = 0; i < 3; ++i) {
            int b = tid + i * 256, g = b >> 7, rem = b & 127, kb = rem >> 4, c4 = rem & 15;
            const float* wb = (g < 3) ? W : R;
            int gm = (g < 3) ? g : g - 3;
            const float* src = wb + (size_t)(k0 + kb * 4) * 3072 + gm * 1024 + n0 + c4 * 4;
            float4 r0 = *(const float4*)(src);
            float4 r1 = *(const float4*)(src + 3072);
            float4 r2 = *(const float4*)(src + 2 * 3072);
            float4 r3 = *(const float4*)(src + 3 * 3072);
            ushort4 s0, s1, s2, s3;
            s0.x=f2bf(r0.x); s0.y=f2bf(r1.x); s0.z=f2bf(r2.x); s0.w=f2bf(r3.x);
            s1.x=f2bf(r0.y); s1.y=f2bf(r1.y); s1.z=f2bf(r2.y); s1.w=f2bf(r3.y);
            s2.x=f2bf(r0.z); s2.y=f2bf(r1.z); s2.z=f2bf(r2.z); s2.w=f2bf(r3.z);
            s3.x=f2bf(r0.w); s3.y=f2bf(r1.w); s3.z=f2bf(r2.w); s3.w=f2bf(r3.w);
            unsigned short* dst = &ldsW[g][0];
            *(ushort4*)&dst[(c4*4+0)*KP + kb*4] = s0;
            *(ushort4*)&dst[(c4*4+1)*KP + kb*4] = s1;
            *(ushort4*)&dst[(c4*4+2)*KP + kb*4] = s2;
            *(ushort4*)&dst[(c4*4+3)*KP + kb*4] = s3;
        }
        __syncthreads();
        shortx8 a_in[4], a_h[4];
        #pragma unroll
        for (int i = 0; i < 4; ++i) {
            a_in[i] = *(const shortx8*)&ldsA[0][(wr*64 + i*16 + lo) * KP + quad*8];
            a_h[i]  = *(const shortx8*)&ldsA[1][(wr*64 + i*16 + lo) * KP + quad*8];
        }
        #pragma unroll
        for (int j = 0; j < 2; ++j) {
            const int nc = (wc*32 + j*16 + lo) * KP + quad*8;
            shortx8 bz  = *(const shortx8*)&ldsW[0][nc];
            shortx8 bre = *(const shortx8*)&ldsW[1][nc];
            shortx8 bh  = *(const shortx8*)&ldsW[2][nc];
            shortx8 rz  = *(const shortx8*)&ldsW[3][nc];
            shortx8 rre = *(const shortx8*)&ldsW[4][nc];
            shortx8 rh  = *(const shortx8*)&ldsW[5][nc];
            #pragma unroll
            for (int i = 0; i < 4; ++i) {
                acc_z[i][j]  = __builtin_amdgcn_mfma_f32_16x16x32_bf16(a_in[i], bz,  acc_z[i][j],  0, 0, 0);
                acc_z[i][j]  = __builtin_amdgcn_mfma_f32_16x16x32_bf16(a_h[i],  rz,  acc_z[i][j],  0, 0, 0);
                acc_r[i][j]  = __builtin_amdgcn_mfma_f32_16x16x32_bf16(a_in[i], bre, acc_r[i][j],  0, 0, 0);
                acc_r[i][j]  = __builtin_amdgcn_mfma_f32_16x16x32_bf16(a_h[i],  rre, acc_r[i][j],  0, 0, 0);
                acc_xh[i][j] = __builtin_amdgcn_mfma_f32_16x16x32_bf16(a_in[i], bh,  acc_xh[i][j], 0, 0, 0);
                acc_rh[i][j] = __builtin_amdgcn_mfma_f32_16x16x32_bf16(a_h[i],  rh,  acc_rh[i][j], 0, 0, 0);
            }
        }
        __syncthreads();
    }
    #pragma unroll
    for (int j = 0; j < 2; ++j) {
        const int col = n0 + wc*32 + j*16 + lo;
        const float bz  = bias[col]        + bias[3072 + col];
        const float brr = bias[1024 + col] + bias[4096 + col];
        const float b0h = bias[2048 + col];
        const float b1h = bias[5120 + col];
        #pragma unroll
        for (int i = 0; i < 4; ++i) {
            const int rowb = m0 + wr*64 + i*16 + quad*4;
            #pragma unroll
            for (int r = 0; r < 4; ++r) {
                const int row = rowb + r;
                float sz = acc_z[i][j][r]  + bz;
                float sr = acc_r[i][j][r]  + brr;
                float xh = acc_xh[i][j][r] + b0h;
                float rh = acc_rh[i][j][r] + b1h;
                float z   = fminf(fmaxf(0.2f * sz + 0.5f, 0.0f), 1.0f);
                float rr2 = fminf(fmaxf(0.2f * sr + 0.5f, 0.0f), 1.0f);
                float pre = xh + rr2 * rh;
                float e   = __expf(2.0f * pre);
                float th  = 1.0f - 2.0f / (e + 1.0f);
                float hp  = H[(size_t)row * 1024 + col];
                out[(size_t)row * 1024 + col] = z * hp + (1.0f - z) * th;
            }
        }
    }
}

extern "C" void kernel_launch(void* const* d_in, const int* in_sizes, int n_in,
                              void* d_out, int out_size, void* d_ws, size_t ws_size,
                              hipStream_t stream)
{
    const float* X    = (const float*)d_in[0];
    const float* H    = (const float*)d_in[1];
    const float* W    = (const float*)d_in[2];
    const float* R    = (const float*)d_in[3];
    const float* bias = (const float*)d_in[4];
    float* out = (float*)d_out;

    const size_t need = (size_t)(8192 * 1024) * 2 * 2 + (size_t)(3072 * 1024) * 2 * 2; // 46.1 MB
    if (ws_size >= need) {
        unsigned short* Xb = (unsigned short*)d_ws;
        unsigned short* Hb = Xb + (size_t)8192 * 1024;
        unsigned short* Wt = Hb + (size_t)8192 * 1024;
        unsigned short* Rt = Wt + (size_t)3072 * 1024;
        hipLaunchKernelGGL(prep_kernel, dim3(16384 + 1536), dim3(256), 0, stream,
                           X, H, W, R, Xb, Hb, Wt, Rt);
        hipLaunchKernelGGL(gru_mfma_kernel, dim3(1024), dim3(256), 0, stream,
                           Xb, Hb, Wt, Rt, bias, out);
    } else {
        hipLaunchKernelGGL(gru_fused_kernel, dim3(1024), dim3(256), 0, stream, X, H, W, R, bias, out);
    }
}